// Round 8
// baseline (160.454 us; speedup 1.0000x reference)
//
#include <hip/hip_runtime.h>
#include <hip/hip_bf16.h>
#include <math.h>
#include <stdint.h>

#define B_    2
#define S_    2048
#define HID_  768
#define NH_   12
#define HD_   64
#define NROWS (B_ * S_)                    // 4096
#define N_HID_ELEM (NROWS * HID_)          // 3145728
#define N_W_ELEM   (HID_ * HID_)           // 589824

// attention LDS geometry: 224 staged keys, row stride 232
#define KW   224
#define KSTR 232
// gemm LDS row stride (64 + 8 pad): 144B rows, conflict-light b128 access
#define LSTR 72

typedef __bf16 bf16x8 __attribute__((ext_vector_type(8)));
typedef float  floatx4 __attribute__((ext_vector_type(4)));

// read 16 fp32 from g, convert, store 16 bf16 to LDS at l (two b128)
__device__ __forceinline__ void cvt_store16(const float* __restrict__ g,
                                            __hip_bfloat16* __restrict__ l)
{
    floatx4 v0 = *reinterpret_cast<const floatx4*>(g);
    floatx4 v1 = *reinterpret_cast<const floatx4*>(g + 4);
    floatx4 v2 = *reinterpret_cast<const floatx4*>(g + 8);
    floatx4 v3 = *reinterpret_cast<const floatx4*>(g + 12);
    __hip_bfloat16 o[16];
#pragma unroll
    for (int i = 0; i < 4; ++i) {
        o[i]      = __float2bfloat16(v0[i]);
        o[4 + i]  = __float2bfloat16(v1[i]);
        o[8 + i]  = __float2bfloat16(v2[i]);
        o[12 + i] = __float2bfloat16(v3[i]);
    }
    *reinterpret_cast<bf16x8*>(l)     = *reinterpret_cast<bf16x8*>(o);
    *reinterpret_cast<bf16x8*>(l + 8) = *reinterpret_cast<bf16x8*>(o + 8);
}

// copy 16 bf16 global -> LDS (two b128)
__device__ __forceinline__ void copy_store16(const __hip_bfloat16* __restrict__ g,
                                             __hip_bfloat16* __restrict__ l)
{
    bf16x8 v0 = *reinterpret_cast<const bf16x8*>(g);
    bf16x8 v1 = *reinterpret_cast<const bf16x8*>(g + 8);
    *reinterpret_cast<bf16x8*>(l)     = v0;
    *reinterpret_cast<bf16x8*>(l + 8) = v1;
}

// ---------------------------------------------------------------------------
// 64x64-tile GEMM with in-flight fp32->bf16 conversion during staging.
// C[m][n] = sum_k A[m][k] * W[n][k]; W is fp32 [N][K].
// ROPE=1: A fp32 (hidden); epilogue writes Q,Qr (bf16).
// ROPE=0: A bf16 (AO from attn); epilogue writes fp32 Cf.
// Staging: thread t owns row t>>2, k-segment (t&3)*16 (lane-contiguous
// 64B fp32 reads). LDS stride 72 elems -> no ds_write/b128-read conflicts.
// Grid (M/64, N/64) = (64,12) = 768 blocks -> ~3 blocks/CU co-resident.
// ---------------------------------------------------------------------------
template<int ROPE>
__global__ __launch_bounds__(256) void gemm64(
    const void* __restrict__ Araw,
    const float* __restrict__ Wf,
    __hip_bfloat16* __restrict__ C,        // ROPE: Q
    __hip_bfloat16* __restrict__ C2,       // ROPE: Qr
    float* __restrict__ Cf,                // !ROPE
    const int* __restrict__ pos_idx,
    int M, int N, int K)
{
    __shared__ __align__(16) __hip_bfloat16 Alds[64 * LSTR];
    __shared__ __align__(16) __hip_bfloat16 Wlds[64 * LSTR];

    const int tid  = threadIdx.x;
    const int wv   = tid >> 6;
    const int lane = tid & 63;
    const int l16  = lane & 15;
    const int quad = lane >> 4;
    const int m0 = blockIdx.x * 64;
    const int n0 = blockIdx.y * 64;

    const int trow = tid >> 2;             // 0..63
    const int tk   = (tid & 3) * 16;       // 0,16,32,48

    const float* gW            = Wf + (size_t)(n0 + trow) * K + tk;
    const float* gAf           = (const float*)Araw + (size_t)(m0 + trow) * K + tk;
    const __hip_bfloat16* gAb  = (const __hip_bfloat16*)Araw + (size_t)(m0 + trow) * K + tk;

    __hip_bfloat16* lA = &Alds[trow * LSTR + tk];
    __hip_bfloat16* lW = &Wlds[trow * LSTR + tk];

    floatx4 acc[4] = {};
    const int ra = wv * 16 + l16;          // A-fragment row for this lane

    for (int k0 = 0; k0 < K; k0 += 64) {
        if (ROPE) cvt_store16(gAf + k0, lA);
        else      copy_store16(gAb + k0, lA);
        cvt_store16(gW + k0, lW);
        __syncthreads();

#pragma unroll
        for (int ks = 0; ks < 2; ++ks) {
            bf16x8 a = *reinterpret_cast<const bf16x8*>(
                &Alds[ra * LSTR + ks * 32 + quad * 8]);
#pragma unroll
            for (int u = 0; u < 4; ++u) {
                bf16x8 w = *reinterpret_cast<const bf16x8*>(
                    &Wlds[(u * 16 + l16) * LSTR + ks * 32 + quad * 8]);
                acc[u] = __builtin_amdgcn_mfma_f32_16x16x32_bf16(a, w, acc[u], 0, 0, 0);
            }
        }
        __syncthreads();
    }

    // epilogue: D row = wv*16 + quad*4 + r, col = n0 + u*16 + l16
    if (ROPE) {
#pragma unroll
        for (int r = 0; r < 4; ++r) {
            int m = m0 + wv * 16 + quad * 4 + r;
            int s = m & (S_ - 1);
            float pos = (float)pos_idx[s];
#pragma unroll
            for (int u = 0; u < 2; ++u) {
                float f = (float)(u * 16 + l16);                 // 0..31
                float inv = exp2f(f * (-0.41524101186092024f)); // -log2(1e4)/32
                float sn, cs;
                sincosf(pos * inv, &sn, &cs);
                float q0 = acc[u][r];
                float q1 = acc[u + 2][r];
                size_t base = (size_t)m * HID_ + n0 + u * 16 + l16;
                C [base]      = __float2bfloat16(q0);
                C [base + 32] = __float2bfloat16(q1);
                C2[base]      = __float2bfloat16(q0 * cs - q1 * sn);
                C2[base + 32] = __float2bfloat16(q1 * cs + q0 * sn);
            }
        }
    } else {
#pragma unroll
        for (int u = 0; u < 4; ++u)
#pragma unroll
            for (int r = 0; r < 4; ++r) {
                int row = m0 + wv * 16 + quad * 4 + r;
                int col = n0 + u * 16 + l16;
                Cf[(size_t)row * N + col] = acc[u][r];
            }
    }
}

// ---------------------------------------------------------------------------
// Banded attention (unchanged -- passed r5/r6/r7).
// ---------------------------------------------------------------------------
__global__ __launch_bounds__(256) void attn_kernel(
    const __hip_bfloat16* __restrict__ Q,    // pre-rope  (= V)
    const __hip_bfloat16* __restrict__ Qr,   // post-rope (= Q = K)
    __hip_bfloat16* __restrict__ O)
{
    __shared__ __align__(16) __hip_bfloat16 Vt[64][KSTR];   // [dim][window]
    __shared__ __align__(16) __hip_bfloat16 Pl[64][KSTR];   // [row][window]

    const int bh = blockIdx.y;
    const int b  = bh / NH_;
    const int h  = bh % NH_;
    const int i0 = blockIdx.x * 64;
    const int tid = threadIdx.x;

    for (int idx = tid; idx < KW * 64; idx += 256) {
        int w = idx >> 6;
        int d = idx & 63;
        int j = i0 - 64 + w;
        int jc = min(max(j, 0), S_ - 1);
        Vt[d][w] = Q[((size_t)(b * S_ + jc)) * HID_ + h * HD_ + d];
    }
    __syncthreads();

    const int wv   = tid >> 6;
    const int lane = tid & 63;
    const int l16  = lane & 15;
    const int quad = lane >> 4;

    // ---- QK^T over the 10 tiles intersecting this wave's band ----
    floatx4 sc[10] = {};
    const __hip_bfloat16* qrow =
        Qr + ((size_t)(b * S_ + i0 + wv * 16 + l16)) * HID_ + h * HD_ + quad * 8;
#pragma unroll
    for (int ks = 0; ks < 2; ++ks) {
        bf16x8 a = *reinterpret_cast<const bf16x8*>(qrow + ks * 32);
#pragma unroll
        for (int t = 0; t < 10; ++t) {
            int j = i0 - 64 + (wv + t) * 16 + l16;
            int jc = min(max(j, 0), S_ - 1);
            bf16x8 bfr = *reinterpret_cast<const bf16x8*>(
                Qr + ((size_t)(b * S_ + jc)) * HID_ + h * HD_ + ks * 32 + quad * 8);
            sc[t] = __builtin_amdgcn_mfma_f32_16x16x32_bf16(a, bfr, sc[t], 0, 0, 0);
        }
    }

    // ---- masked softmax per row ----
    const float scale = 0.125f;
    float denom[4];
#pragma unroll
    for (int r = 0; r < 4; ++r) {
        const int R = wv * 16 + quad * 4 + r;
        float xv[10];
        float mx = -3.0e38f;
#pragma unroll
        for (int t = 0; t < 10; ++t) {
            int w = (wv + t) * 16 + l16;
            int j = i0 - 64 + w;
            bool valid = (w >= R) && (w <= R + 128) && (j >= 0) && (j < S_);
            float x = valid ? sc[t][r] * scale : -1.0e30f;
            xv[t] = x;
            mx = fmaxf(mx, x);
        }
#pragma unroll
        for (int msk = 1; msk < 16; msk <<= 1) mx = fmaxf(mx, __shfl_xor(mx, msk, 64));
        float sum = 0.f;
#pragma unroll
        for (int t = 0; t < 10; ++t) {
            float p = __expf(xv[t] - mx);
            sum += p;
            Pl[R][(wv + t) * 16 + l16] = __float2bfloat16(p);
        }
#pragma unroll
        for (int msk = 1; msk < 16; msk <<= 1) sum += __shfl_xor(sum, msk, 64);
        denom[r] = sum;
    }
    __syncthreads();

    // ---- PV over the wave's 160-wide band ----
    floatx4 oacc[4] = {};
#pragma unroll
    for (int c = 0; c < 5; ++c) {
        const int base = wv * 16 + c * 32;
        bf16x8 a = *reinterpret_cast<const bf16x8*>(&Pl[wv * 16 + l16][base + quad * 8]);
#pragma unroll
        for (int u = 0; u < 4; ++u) {
            bf16x8 bfr = *reinterpret_cast<const bf16x8*>(&Vt[u * 16 + l16][base + quad * 8]);
            oacc[u] = __builtin_amdgcn_mfma_f32_16x16x32_bf16(a, bfr, oacc[u], 0, 0, 0);
        }
    }

#pragma unroll
    for (int u = 0; u < 4; ++u)
#pragma unroll
        for (int r = 0; r < 4; ++r) {
            int row = i0 + wv * 16 + quad * 4 + r;
            int col = u * 16 + l16;
            O[((size_t)(b * S_ + row)) * HID_ + h * HD_ + col] =
                __float2bfloat16(oacc[u][r] / denom[r]);
        }
}

// ---------------------------------------------------------------------------
extern "C" void kernel_launch(void* const* d_in, const int* in_sizes, int n_in,
                              void* d_out, int out_size, void* d_ws, size_t ws_size,
                              hipStream_t stream)
{
    int ih = -1, iw1 = -1, iw2 = -1, ip = -1;
    for (int i = 0; i < n_in; ++i) {
        int s = in_sizes[i];
        if      (s == N_HID_ELEM && ih < 0) ih = i;
        else if (s == N_W_ELEM)  { if (iw1 < 0) iw1 = i; else if (iw2 < 0) iw2 = i; }
        else if (s == S_ && ip < 0) ip = i;
    }
    if (ih < 0)  ih = 0;
    if (iw1 < 0) iw1 = 1;
    if (iw2 < 0) iw2 = 2;
    if (ip < 0)  ip = 5;

    const float* hidden = (const float*)d_in[ih];
    const float* w1     = (const float*)d_in[iw1];
    const float* w2     = (const float*)d_in[iw2];
    const int*   pos    = (const int*)d_in[ip];

    __hip_bfloat16* Q  = (__hip_bfloat16*)d_ws;
    __hip_bfloat16* Qr = Q  + N_HID_ELEM;
    __hip_bfloat16* AO = Qr + N_HID_ELEM;

    dim3 gblk(NROWS / 64, HID_ / 64);   // (64, 12) = 768 blocks

    // GEMM1 (fp32 hidden x fp32 Wq, convert in staging) + fused RoPE -> Q, Qr
    gemm64<1><<<gblk, 256, 0, stream>>>(hidden, w1, Q, Qr, nullptr, pos,
                                        NROWS, HID_, HID_);

    attn_kernel<<<dim3(S_ / 64, B_ * NH_), 256, 0, stream>>>(Q, Qr, AO);

    // GEMM2 (bf16 AO x fp32 Wo) -> fp32 out
    gemm64<0><<<gblk, 256, 0, stream>>>(AO, w2, nullptr, nullptr, (float*)d_out,
                                        nullptr, NROWS, HID_, HID_);
}

// Round 9
// 143.598 us; speedup vs baseline: 1.1174x; 1.1174x over previous
//
#include <hip/hip_runtime.h>
#include <hip/hip_bf16.h>
#include <math.h>
#include <stdint.h>

#define B_    2
#define S_    2048
#define HID_  768
#define NH_   12
#define HD_   64
#define NROWS (B_ * S_)                    // 4096
#define N_HID_ELEM (NROWS * HID_)          // 3145728
#define N_W_ELEM   (HID_ * HID_)           // 589824

// attention LDS geometry: 224 staged keys, row stride 232
#define KW   224
#define KSTR 232

typedef __bf16 bf16x8 __attribute__((ext_vector_type(8)));
typedef float  floatx4 __attribute__((ext_vector_type(4)));

// fp32 -> bf16 conversion of hidden + Wq + Wo, x4 vectorized
__global__ void convert_inputs_kernel(const float* __restrict__ src_hidden,
                                      const float* __restrict__ src_w1,
                                      const float* __restrict__ src_w2,
                                      __hip_bfloat16* __restrict__ Hb,
                                      __hip_bfloat16* __restrict__ Wqb,
                                      __hip_bfloat16* __restrict__ Wob)
{
    int i = blockIdx.x * blockDim.x + threadIdx.x;   // float4 index
    const float* src;
    __hip_bfloat16* dst;
    int off;
    const int NH4 = N_HID_ELEM / 4, NW4 = N_W_ELEM / 4;
    if (i < NH4)           { src = src_hidden; dst = Hb;  off = i; }
    else if (i < NH4+NW4)  { src = src_w1;     dst = Wqb; off = i - NH4; }
    else if (i < NH4+2*NW4){ src = src_w2;     dst = Wob; off = i - NH4 - NW4; }
    else return;
    float4 v = reinterpret_cast<const float4*>(src)[off];
    __hip_bfloat16 o[4] = { __float2bfloat16(v.x), __float2bfloat16(v.y),
                            __float2bfloat16(v.z), __float2bfloat16(v.w) };
    *reinterpret_cast<uint64_t*>(dst + 4 * (size_t)off) = *reinterpret_cast<uint64_t*>(o);
}

__device__ __forceinline__ void gload_lds16(const __hip_bfloat16* g, __hip_bfloat16* l)
{
    __builtin_amdgcn_global_load_lds(
        (const __attribute__((address_space(1))) void*)g,
        (__attribute__((address_space(3))) void*)l, 16, 0, 0);
}

// ---------------------------------------------------------------------------
// 64x64-tile GEMM, intra-block split-K(2) + double-buffered LDS.
// C[m][n] = sum_k A[m][k] * W[n][k], K=768. 512 threads = 2 k-groups x 4 waves.
// Group kg covers k in [kg*384, kg*384+384), 6 iters of BK=64 (two 32-halves).
// Double-buffer: stage(it+1) issued before compute(it); the barrier's vmcnt
// drain lands after compute -> load latency overlapped.
// End: kg1 dumps accs to LDS (f32), kg0 adds and runs the epilogue.
// ROPE=1: epilogue writes Q,Qr (bf16).  ROPE=0: writes fp32 Cf.
// ---------------------------------------------------------------------------
template<int ROPE>
__global__ __launch_bounds__(512) void gemm64k2(
    const __hip_bfloat16* __restrict__ A,
    const __hip_bfloat16* __restrict__ W,
    __hip_bfloat16* __restrict__ C,        // ROPE: Q
    __hip_bfloat16* __restrict__ C2,       // ROPE: Qr
    float* __restrict__ Cf,                // !ROPE
    const int* __restrict__ pos_idx,
    int M, int N, int K)
{
    // [kg][buf][half][row][32]  (row stride 64B; 2-way bank alias = free)
    __shared__ __align__(16) __hip_bfloat16 Ald[2][2][2][64][32];  // 32 KB
    __shared__ __align__(16) __hip_bfloat16 Wld[2][2][2][64][32];  // 32 KB

    const int tid  = threadIdx.x;
    const int kg   = tid >> 8;             // k-group 0/1
    const int wv4  = (tid >> 6) & 3;       // wave within group
    const int lane = tid & 63;
    const int l16  = lane & 15;
    const int quad = lane >> 4;
    const int m0 = blockIdx.x * 64;
    const int n0 = blockIdx.y * 64;

    // staging geometry within group: chunk c in [0,256): row=c>>2, col8=(c&3)*8
    const int c   = wv4 * 64 + lane;
    const int sr  = c >> 2;
    const int sc8 = (c & 3) * 8;
    const int kbase = kg * 384;

    const __hip_bfloat16* gA = A + (size_t)(m0 + sr) * K + kbase + sc8;
    const __hip_bfloat16* gW = W + (size_t)(n0 + sr) * K + kbase + sc8;

    floatx4 acc[4] = {};
    const int ra = wv4 * 16 + l16;         // A-fragment row for this lane

    // prologue: stage it=0 into buf 0
    gload_lds16(gA,      &Ald[kg][0][0][wv4 * 16][0]);
    gload_lds16(gA + 32, &Ald[kg][0][1][wv4 * 16][0]);
    gload_lds16(gW,      &Wld[kg][0][0][wv4 * 16][0]);
    gload_lds16(gW + 32, &Wld[kg][0][1][wv4 * 16][0]);

#pragma unroll
    for (int it = 0; it < 6; ++it) {
        const int cur = it & 1;
        __syncthreads();                   // drains glds for buf 'cur'
        if (it + 1 < 6) {                  // issue next into other buf
            const int nb = (it + 1) & 1;
            const int ko = (it + 1) * 64;
            gload_lds16(gA + ko,      &Ald[kg][nb][0][wv4 * 16][0]);
            gload_lds16(gA + ko + 32, &Ald[kg][nb][1][wv4 * 16][0]);
            gload_lds16(gW + ko,      &Wld[kg][nb][0][wv4 * 16][0]);
            gload_lds16(gW + ko + 32, &Wld[kg][nb][1][wv4 * 16][0]);
        }
#pragma unroll
        for (int ks = 0; ks < 2; ++ks) {
            bf16x8 a = *reinterpret_cast<const bf16x8*>(&Ald[kg][cur][ks][ra][quad * 8]);
#pragma unroll
            for (int u = 0; u < 4; ++u) {
                bf16x8 w = *reinterpret_cast<const bf16x8*>(
                    &Wld[kg][cur][ks][u * 16 + l16][quad * 8]);
                acc[u] = __builtin_amdgcn_mfma_f32_16x16x32_bf16(a, w, acc[u], 0, 0, 0);
            }
        }
    }

    // ---- cross-group reduction through LDS (reuse Ald region: 64x68 f32) ----
    __syncthreads();
    float* Red = reinterpret_cast<float*>(&Ald[0][0][0][0][0]);   // 17.4 KB < 32 KB
    if (kg == 1) {
#pragma unroll
        for (int u = 0; u < 4; ++u)
#pragma unroll
            for (int r = 0; r < 4; ++r)
                Red[(wv4 * 16 + quad * 4 + r) * 68 + u * 16 + l16] = acc[u][r];
    }
    __syncthreads();
    if (kg == 1) return;
#pragma unroll
    for (int u = 0; u < 4; ++u)
#pragma unroll
        for (int r = 0; r < 4; ++r)
            acc[u][r] += Red[(wv4 * 16 + quad * 4 + r) * 68 + u * 16 + l16];

    // ---- epilogue (kg0 only): D row = wv4*16+quad*4+r, col = n0+u*16+l16 ----
    if (ROPE) {
#pragma unroll
        for (int r = 0; r < 4; ++r) {
            int m = m0 + wv4 * 16 + quad * 4 + r;
            int s = m & (S_ - 1);
            float pos = (float)pos_idx[s];
#pragma unroll
            for (int u = 0; u < 2; ++u) {
                float f = (float)(u * 16 + l16);                 // 0..31
                float inv = exp2f(f * (-0.41524101186092024f)); // -log2(1e4)/32
                float sn, cs;
                sincosf(pos * inv, &sn, &cs);
                float q0 = acc[u][r];
                float q1 = acc[u + 2][r];
                size_t base = (size_t)m * HID_ + n0 + u * 16 + l16;
                C [base]      = __float2bfloat16(q0);
                C [base + 32] = __float2bfloat16(q1);
                C2[base]      = __float2bfloat16(q0 * cs - q1 * sn);
                C2[base + 32] = __float2bfloat16(q1 * cs + q0 * sn);
            }
        }
    } else {
#pragma unroll
        for (int u = 0; u < 4; ++u)
#pragma unroll
            for (int r = 0; r < 4; ++r) {
                int row = m0 + wv4 * 16 + quad * 4 + r;
                int col = n0 + u * 16 + l16;
                Cf[(size_t)row * N + col] = acc[u][r];
            }
    }
}

// ---------------------------------------------------------------------------
// Banded attention; vectorized Vt staging + LDS-repacked O writeback.
// ---------------------------------------------------------------------------
__global__ __launch_bounds__(256) void attn_kernel(
    const __hip_bfloat16* __restrict__ Q,    // pre-rope  (= V)
    const __hip_bfloat16* __restrict__ Qr,   // post-rope (= Q = K)
    __hip_bfloat16* __restrict__ O)
{
    __shared__ __align__(16) __hip_bfloat16 Vt[64][KSTR];   // [dim][window]
    __shared__ __align__(16) __hip_bfloat16 Pl[64][KSTR];   // [row][window]

    const int bh = blockIdx.y;
    const int b  = bh / NH_;
    const int h  = bh % NH_;
    const int i0 = blockIdx.x * 64;
    const int tid = threadIdx.x;

    // stage V^T: thread handles (w, d8) -> one bf16x8 load + 8 scalar ds writes
    for (int idx = tid; idx < KW * 8; idx += 256) {
        int w  = idx >> 3;
        int d8 = (idx & 7) * 8;
        int j  = i0 - 64 + w;
        int jc = min(max(j, 0), S_ - 1);
        bf16x8 v = *reinterpret_cast<const bf16x8*>(
            Q + ((size_t)(b * S_ + jc)) * HID_ + h * HD_ + d8);
        const __hip_bfloat16* ve = reinterpret_cast<const __hip_bfloat16*>(&v);
#pragma unroll
        for (int e = 0; e < 8; ++e) Vt[d8 + e][w] = ve[e];
    }
    __syncthreads();

    const int wv   = tid >> 6;
    const int lane = tid & 63;
    const int l16  = lane & 15;
    const int quad = lane >> 4;

    // ---- QK^T over the 10 tiles intersecting this wave's band ----
    floatx4 sc[10] = {};
    const __hip_bfloat16* qrow =
        Qr + ((size_t)(b * S_ + i0 + wv * 16 + l16)) * HID_ + h * HD_ + quad * 8;
#pragma unroll
    for (int ks = 0; ks < 2; ++ks) {
        bf16x8 a = *reinterpret_cast<const bf16x8*>(qrow + ks * 32);
#pragma unroll
        for (int t = 0; t < 10; ++t) {
            int j = i0 - 64 + (wv + t) * 16 + l16;
            int jc = min(max(j, 0), S_ - 1);
            bf16x8 bfr = *reinterpret_cast<const bf16x8*>(
                Qr + ((size_t)(b * S_ + jc)) * HID_ + h * HD_ + ks * 32 + quad * 8);
            sc[t] = __builtin_amdgcn_mfma_f32_16x16x32_bf16(a, bfr, sc[t], 0, 0, 0);
        }
    }

    // ---- masked softmax per row ----
    const float scale = 0.125f;
    float denom[4];
#pragma unroll
    for (int r = 0; r < 4; ++r) {
        const int R = wv * 16 + quad * 4 + r;
        float xv[10];
        float mx = -3.0e38f;
#pragma unroll
        for (int t = 0; t < 10; ++t) {
            int w = (wv + t) * 16 + l16;
            int j = i0 - 64 + w;
            bool valid = (w >= R) && (w <= R + 128) && (j >= 0) && (j < S_);
            float x = valid ? sc[t][r] * scale : -1.0e30f;
            xv[t] = x;
            mx = fmaxf(mx, x);
        }
#pragma unroll
        for (int msk = 1; msk < 16; msk <<= 1) mx = fmaxf(mx, __shfl_xor(mx, msk, 64));
        float sum = 0.f;
#pragma unroll
        for (int t = 0; t < 10; ++t) {
            float p = __expf(xv[t] - mx);
            sum += p;
            Pl[R][(wv + t) * 16 + l16] = __float2bfloat16(p);
        }
#pragma unroll
        for (int msk = 1; msk < 16; msk <<= 1) sum += __shfl_xor(sum, msk, 64);
        denom[r] = sum;
    }
    __syncthreads();

    // ---- PV over the wave's 160-wide band ----
    floatx4 oacc[4] = {};
#pragma unroll
    for (int c = 0; c < 5; ++c) {
        const int base = wv * 16 + c * 32;
        bf16x8 a = *reinterpret_cast<const bf16x8*>(&Pl[wv * 16 + l16][base + quad * 8]);
#pragma unroll
        for (int u = 0; u < 4; ++u) {
            bf16x8 bfr = *reinterpret_cast<const bf16x8*>(&Vt[u * 16 + l16][base + quad * 8]);
            oacc[u] = __builtin_amdgcn_mfma_f32_16x16x32_bf16(a, bfr, oacc[u], 0, 0, 0);
        }
    }

    // ---- O writeback via LDS repack (reuse Pl as f32 [64][68]) ----
    __syncthreads();                       // all Pl/Vt reads done
    float* Of = reinterpret_cast<float*>(&Pl[0][0]);
#pragma unroll
    for (int u = 0; u < 4; ++u)
#pragma unroll
        for (int r = 0; r < 4; ++r)
            Of[(wv * 16 + quad * 4 + r) * 68 + u * 16 + l16] = oacc[u][r] / denom[r];
    __syncthreads();
    {
        int row = tid >> 2;
        int seg = (tid & 3) * 16;
        __hip_bfloat16 ob[16];
#pragma unroll
        for (int e = 0; e < 16; ++e)
            ob[e] = __float2bfloat16(Of[row * 68 + seg + e]);
        __hip_bfloat16* dst = O + ((size_t)(b * S_ + i0 + row)) * HID_ + h * HD_ + seg;
        *reinterpret_cast<bf16x8*>(dst)     = *reinterpret_cast<bf16x8*>(ob);
        *reinterpret_cast<bf16x8*>(dst + 8) = *reinterpret_cast<bf16x8*>(ob + 8);
    }
}

// ---------------------------------------------------------------------------
extern "C" void kernel_launch(void* const* d_in, const int* in_sizes, int n_in,
                              void* d_out, int out_size, void* d_ws, size_t ws_size,
                              hipStream_t stream)
{
    int ih = -1, iw1 = -1, iw2 = -1, ip = -1;
    for (int i = 0; i < n_in; ++i) {
        int s = in_sizes[i];
        if      (s == N_HID_ELEM && ih < 0) ih = i;
        else if (s == N_W_ELEM)  { if (iw1 < 0) iw1 = i; else if (iw2 < 0) iw2 = i; }
        else if (s == S_ && ip < 0) ip = i;
    }
    if (ih < 0)  ih = 0;
    if (iw1 < 0) iw1 = 1;
    if (iw2 < 0) iw2 = 2;
    if (ip < 0)  ip = 5;

    const float* hidden = (const float*)d_in[ih];
    const float* w1     = (const float*)d_in[iw1];
    const float* w2     = (const float*)d_in[iw2];
    const int*   pos    = (const int*)d_in[ip];

    __hip_bfloat16* Hb  = (__hip_bfloat16*)d_ws;
    __hip_bfloat16* Wqb = Hb  + N_HID_ELEM;
    __hip_bfloat16* Wob = Wqb + N_W_ELEM;
    __hip_bfloat16* Q   = Wob + N_W_ELEM;
    __hip_bfloat16* Qr  = Q   + N_HID_ELEM;
    __hip_bfloat16* AO  = Hb;   // Hb dead after gemm1

    int conv4 = (N_HID_ELEM + 2 * N_W_ELEM) / 4;
    convert_inputs_kernel<<<(conv4 + 255) / 256, 256, 0, stream>>>(
        hidden, w1, w2, Hb, Wqb, Wob);

    dim3 gblk(NROWS / 64, HID_ / 64);   // (64, 12) = 768 blocks

    // GEMM1 + fused RoPE -> Q, Qr
    gemm64k2<1><<<gblk, 512, 0, stream>>>(Hb, Wqb, Q, Qr, nullptr, pos,
                                          NROWS, HID_, HID_);

    attn_kernel<<<dim3(S_ / 64, B_ * NH_), 256, 0, stream>>>(Q, Qr, AO);

    // GEMM2 -> fp32 out
    gemm64k2<0><<<gblk, 512, 0, stream>>>(AO, Wob, nullptr, nullptr, (float*)d_out,
                                          nullptr, NROWS, HID_, HID_);
}